// Round 13
// baseline (524.940 us; speedup 1.0000x reference)
//
#include <hip/hip_runtime.h>
#include <math.h>

#define NROWS 65536      // B*T
#define DIM   64
#define KCODE 1024
#define TAU_M 2.5e-3f    // margin threshold: eps ~6e-4 (split+accum+4bit-trunc), >4x headroom

typedef __attribute__((ext_vector_type(8))) short short8;
typedef __bf16 bf16_t;
typedef bf16_t bf16x8 __attribute__((ext_vector_type(8)));
typedef __attribute__((ext_vector_type(4))) float f32x4;

union B8 { bf16x8 v; short8 s; ushort u[8]; };

// ws layout (bytes):
//   [0       .. 262143 ]  ushort emb_frag (64 tiles x 4KB)
//   [262144  .. 266239 ]  float  e2h[1024] = -(||e||^2 - 64)/2
//   [266240  .. 270335 ]  int    counts[1024]
//   [270336  .. 270339 ]  float  sse
//   [270340  .. 270343 ]  uint   nflag
//   [270344  .. 270347 ]  uint   ftick            (fixup->finalize ticket)
//   [270348  .. 274443 ]  uint   rtick[1024]      (per-rowblock merge tickets)
//   [274448  .. 1323023]  float2 wsM[2][65536]    per-half per-row (m1,m2)
//   [1323024 .. 1585167]  ushort wsC[2][65536]    per-half per-row argmax code
//   [1585168 .. 1847311]  float  wsZ2[65536]      per-row ||z||^2
//   [1847312 .. 1978383]  ushort list[NROWS]      flagged row ids, compacted
#define WS_EMBF(ws)   ((ushort*)(ws))
#define WS_E2H(ws)    ((float*)((char*)(ws) + 262144))
#define WS_COUNTS(ws) ((int*)((char*)(ws) + 266240))
#define WS_SSE(ws)    ((float*)((char*)(ws) + 270336))
#define WS_NFLAG(ws)  ((unsigned int*)((char*)(ws) + 270340))
#define WS_FTICK(ws)  ((unsigned int*)((char*)(ws) + 270344))
#define WS_RTICK(ws)  ((unsigned int*)((char*)(ws) + 270348))
#define WS_M(ws)      ((float2*)((char*)(ws) + 274448))
#define WS_C(ws)      ((ushort*)((char*)(ws) + 1323024))
#define WS_Z2(ws)     ((float*)((char*)(ws) + 1585168))
#define WS_LIST(ws)   ((ushort*)((char*)(ws) + 1847312))

__device__ __forceinline__ ushort f2bf(float x) {
  unsigned u = __float_as_uint(x);
  u += 0x7FFFu + ((u >> 16) & 1u);           // RNE
  return (ushort)(u >> 16);
}
__device__ __forceinline__ float bf2f(ushort h) {
  return __uint_as_float(((unsigned)h) << 16);
}

// ---------------------------------------------------------------- init ----
// grid 64 blocks x 256 threads; block = one 16-code tile (4KB fragment image).
__global__ __launch_bounds__(256) void vq_init(const float* __restrict__ emb, void* ws) {
  __shared__ __align__(16) ushort timg[2048];   // 4KB tile image
  __shared__ float e2p[256];

  const int g = blockIdx.x, t = threadIdx.x;    // g = global tile (16 codes)
  const int cl = t & 15;                        // local code (= MFMA col)
  const int d0 = (t >> 4) * 4;                  // dim range start
  const int gc = g * 16 + cl;

  const float4 v = *(const float4*)(emb + (size_t)gc * DIM + d0);
  float xs[4] = {v.x, v.y, v.z, v.w};
  float acc = 0.f;
#pragma unroll
  for (int u = 0; u < 4; ++u) {
    int d = d0 + u;
    float x = xs[u];
    ushort hs = f2bf(x);
    ushort ls = f2bf(x - bf2f(hs));
    int ks = d >> 5, kq = (d >> 3) & 3, e = d & 7;
    int lane = cl + kq * 16;
    int off = ks * 1024 + lane * 8 + e;         // ushort units within tile image
    timg[off] = hs;
    timg[off + 512] = ls;
    acc += x * x;
  }
  e2p[t] = acc;
  __syncthreads();
  if (t < 16) {
    float s = 0.f;
#pragma unroll
    for (int j = 0; j < 16; ++j) s += e2p[t + 16 * j];
    WS_E2H(ws)[g * 16 + t] = -0.5f * (s - 64.0f);   // shifted offset
    WS_COUNTS(ws)[g * 16 + t] = 0;
  }
  if (g < 4) WS_RTICK(ws)[g * 256 + t] = 0u;        // zero merge tickets
  if (g == 0 && t == 0) { *WS_SSE(ws) = 0.f; *WS_NFLAG(ws) = 0u; *WS_FTICK(ws) = 0u; }
  __syncthreads();
  ((int4*)WS_EMBF(ws))[g * 256 + t] = ((const int4*)timg)[t];
}

// ---------------------------------------------------------------- main ----
// grid 2048 = (rowblk 0..1023) x (code-half 0..1): block = 64 rows x 512 codes
// (R11's proven-47us geometry). 4 waves = 2 row-halves x 2 code-quarters;
// wave = 32 rows x 256 codes (16 tiles), ~60 persistent regs.
// Cross-half merge runs INSIDE main via a per-rowblock ticket: second
// finisher merges + does flag/counts/SSE/gather (no separate merge kernel —
// R11's vq_merge serialized ~30us after the full grid).
__global__ __launch_bounds__(256, 1) void vq_main(const float* __restrict__ z,
                                                  const float* __restrict__ emb,
                                                  void* ws,
                                                  float* __restrict__ outp) {
  __shared__ float  e2s[KCODE];  // 4KB
  __shared__ float2 redm[128];   // [wq][64 rows] top-2 m
  __shared__ int    redi[128];   // [wq][64 rows] argmax code
  __shared__ float  z2l[64];
  __shared__ int    win[64];
  __shared__ unsigned tick;

  const int tid  = threadIdx.x;
  const int lane = tid & 63, w = tid >> 6;
  const int wr = w >> 1, wq = w & 1;
  const int col  = lane & 15, kq = lane >> 4;
  const int rowblk = blockIdx.x >> 1, half = blockIdx.x & 1;
  const int rowbase = rowblk * 64 + wr * 32;
  const int tbase = half * 32 + wq * 16;         // first global tile of this wave

  // stage e2h -> LDS (4KB)
  ((float4*)e2s)[tid] = ((const float4*)WS_E2H(ws))[tid];

  // A fragments: 2 row-groups-of-16 x 2 ksteps, hi+lo, in registers all kernel.
  B8 ah[2][2], al[2][2];
  float z2p[2];
#pragma unroll
  for (int g = 0; g < 2; ++g) {
    int row = rowbase + g * 16 + col;
    const float* zr = z + (size_t)row * DIM;
    float acc2 = 0.f;
#pragma unroll
    for (int ks = 0; ks < 2; ++ks) {
      const float4* p = (const float4*)(zr + ks * 32 + kq * 8);
      float4 x0 = p[0], x1 = p[1];
      float vv[8] = {x0.x, x0.y, x0.z, x0.w, x1.x, x1.y, x1.z, x1.w};
#pragma unroll
      for (int e = 0; e < 8; ++e) {
        ushort hs = f2bf(vv[e]);
        ah[g][ks].u[e] = hs;
        al[g][ks].u[e] = f2bf(vv[e] - bf2f(hs));
        acc2 = fmaf(vv[e], vv[e], acc2);
      }
    }
    z2p[g] = acc2;
  }
#pragma unroll
  for (int g = 0; g < 2; ++g) {
    z2p[g] += __shfl_xor(z2p[g], 16, 64);
    z2p[g] += __shfl_xor(z2p[g], 32, 64);
  }

  float b1[8], b2[8];   // packed top-2 of m = z.e - (e^2-64)/2; low 4 bits = 15-t
#pragma unroll
  for (int q = 0; q < 8; ++q) { b1[q] = -3.4e38f; b2[q] = -3.4e38f; }

  __syncthreads();      // e2s ready

  // single incremented base + imm offsets (1024/2048/3072) for the 4 frag loads
  const char* bb = (const char*)WS_EMBF(ws) + (size_t)tbase * 4096 + lane * 16;
  const int cidx0 = tbase * 16 + col;

#pragma unroll 4
  for (int t = 0; t < 16; ++t) {
    B8 bh0, bl0, bh1, bl1;
    bh0.s = *(const short8*)(bb);
    bl0.s = *(const short8*)(bb + 1024);
    bh1.s = *(const short8*)(bb + 2048);
    bl1.s = *(const short8*)(bb + 3072);
    bb += 4096;

    float cinit = e2s[cidx0 + t * 16];
    f32x4 cc = {cinit, cinit, cinit, cinit};
    f32x4 zz4 = {0.f, 0.f, 0.f, 0.f};
    unsigned invT = 15u - (unsigned)t;

    // 4 independent chains, depth 3 each
    f32x4 p0 = __builtin_amdgcn_mfma_f32_16x16x32_bf16(ah[0][0].v, bh0.v, cc, 0, 0, 0);
    f32x4 p1 = __builtin_amdgcn_mfma_f32_16x16x32_bf16(ah[1][0].v, bh0.v, cc, 0, 0, 0);
    f32x4 q0 = __builtin_amdgcn_mfma_f32_16x16x32_bf16(ah[0][0].v, bl0.v, zz4, 0, 0, 0);
    f32x4 q1 = __builtin_amdgcn_mfma_f32_16x16x32_bf16(ah[1][0].v, bl0.v, zz4, 0, 0, 0);
    p0 = __builtin_amdgcn_mfma_f32_16x16x32_bf16(al[0][0].v, bh0.v, p0, 0, 0, 0);
    p1 = __builtin_amdgcn_mfma_f32_16x16x32_bf16(al[1][0].v, bh0.v, p1, 0, 0, 0);
    q0 = __builtin_amdgcn_mfma_f32_16x16x32_bf16(al[0][1].v, bh1.v, q0, 0, 0, 0);
    q1 = __builtin_amdgcn_mfma_f32_16x16x32_bf16(al[1][1].v, bh1.v, q1, 0, 0, 0);
    p0 = __builtin_amdgcn_mfma_f32_16x16x32_bf16(ah[0][1].v, bh1.v, p0, 0, 0, 0);
    p1 = __builtin_amdgcn_mfma_f32_16x16x32_bf16(ah[1][1].v, bh1.v, p1, 0, 0, 0);
    q0 = __builtin_amdgcn_mfma_f32_16x16x32_bf16(ah[0][1].v, bl1.v, q0, 0, 0, 0);
    q1 = __builtin_amdgcn_mfma_f32_16x16x32_bf16(ah[1][1].v, bl1.v, q1, 0, 0, 0);

#pragma unroll
    for (int g = 0; g < 2; ++g) {
      f32x4 pv = g ? p1 : p0;
      f32x4 qv = g ? q1 : q0;
#pragma unroll
      for (int r = 0; r < 4; ++r) {
        int q = g * 4 + r;
        float m = pv[r] + qv[r];
        unsigned mb = (__float_as_uint(m) & 0xFFFFFFF0u) | invT;
        float mp = __uint_as_float(mb);
        float nb2 = __builtin_amdgcn_fmed3f(mp, b1[q], b2[q]);
        b1[q] = fmaxf(b1[q], mp);
        b2[q] = nb2;
      }
    }
  }

  // unpack to explicit (m, code) and top-2 merge across the 16 col-lanes
  float m1a[8], m2a[8]; int c1a[8];
#pragma unroll
  for (int q = 0; q < 8; ++q) {
    unsigned u1 = __float_as_uint(b1[q]);
    int T1 = 15 - (int)(u1 & 0xFu);
    float m1 = __uint_as_float(u1 & 0xFFFFFFF0u);
    int   c1 = (tbase + T1) * 16 + col;
    float m2 = __uint_as_float(__float_as_uint(b2[q]) & 0xFFFFFFF0u);
#pragma unroll
    for (int off = 1; off <= 8; off <<= 1) {
      float om1 = __shfl_xor(m1, off, 64);
      float om2 = __shfl_xor(m2, off, 64);
      int   oc1 = __shfl_xor(c1, off, 64);
      bool take = (om1 > m1) || (om1 == m1 && oc1 < c1);
      m2 = __builtin_amdgcn_fmed3f(m1, om1, fmaxf(m2, om2));
      m1 = take ? om1 : m1;
      c1 = take ? oc1 : c1;
    }
    m1a[q] = m1; m2a[q] = m2; c1a[q] = c1;
  }

  if (col == 0) {
#pragma unroll
    for (int q = 0; q < 8; ++q) {
      int row = wr * 32 + (q >> 2) * 16 + kq * 4 + (q & 3);   // block-local 0..63
      redm[wq * 64 + row] = make_float2(m1a[q], m2a[q]);
      redi[wq * 64 + row] = c1a[q];
    }
  }
  if (wq == 0 && kq == 0) {
#pragma unroll
    for (int g = 0; g < 2; ++g) z2l[wr * 32 + g * 16 + col] = z2p[g];
  }
  __syncthreads();

  // merge the 2 code-quarters; write per-half per-row top-2 to ws (wave 0 only)
  if (tid < 64) {
    int row = tid;
    float2 va = redm[row];        int ca = redi[row];
    float2 vb = redm[64 + row];   int cb = redi[64 + row];
    bool take = (vb.x > va.x) || (vb.x == va.x && cb < ca);
    float M1 = take ? vb.x : va.x;
    int   C1 = take ? cb : ca;
    float M2 = __builtin_amdgcn_fmed3f(va.x, vb.x, fmaxf(va.y, vb.y));
    int grow = rowblk * 64 + row;
    WS_M(ws)[half * NROWS + grow] = make_float2(M1, M2);
    WS_C(ws)[half * NROWS + grow] = (ushort)C1;
    if (half == 0) WS_Z2(ws)[grow] = z2l[row];
  }
  __threadfence();                 // release: ws writes visible device-wide
  __syncthreads();
  if (tid == 0) tick = atomicAdd(&WS_RTICK(ws)[rowblk], 1u);
  __syncthreads();

  if (tick == 1) {                 // second finisher merges this row-block
    __threadfence();               // acquire: other half's ws writes
    if (tid < 64) {
      int grow = rowblk * 64 + tid;
      float2 a = WS_M(ws)[grow];
      float2 b = WS_M(ws)[NROWS + grow];
      int   ca = (int)WS_C(ws)[grow];
      int   cb = (int)WS_C(ws)[NROWS + grow];
      bool take = (b.x > a.x);     // half0 codes < half1 codes: tie keeps half0
      float M1 = take ? b.x : a.x;
      int   C1 = take ? cb : ca;
      float M2 = __builtin_amdgcn_fmed3f(a.x, b.x, fmaxf(a.y, b.y));
      bool flg = (M1 - M2) < TAU_M;            // uncertified -> fp64 fixup
      win[tid] = flg ? -1 : C1;
      if (!flg) {
        atomicAdd(&WS_COUNTS(ws)[C1], 1);
      } else {
        unsigned p = atomicAdd(WS_NFLAG(ws), 1u);
        WS_LIST(ws)[p] = (ushort)grow;
      }
      // ||z-e||^2 = ||z||^2 + 64 - 2*m1
      float ssep = flg ? 0.f : (WS_Z2(ws)[grow] + 64.0f - 2.0f * M1);
#pragma unroll
      for (int off = 32; off; off >>= 1) ssep += __shfl_down(ssep, off, 64);
      if (tid == 0) atomicAdd(WS_SSE(ws), ssep);
    }
    __syncthreads();
    // quantized_st == emb[winner] in value: gather write, no z re-read
    int row = tid >> 2, qtr = tid & 3;
    int wv = win[row];
    if (wv >= 0) {
      size_t grow = (size_t)rowblk * 64 + row;
      const float4* ep = (const float4*)(emb + (size_t)wv * DIM) + qtr * 4;
      float4* op = (float4*)(outp + grow * DIM) + qtr * 4;
      op[0] = ep[0]; op[1] = ep[1]; op[2] = ep[2]; op[3] = ep[3];
    }
  }
}

// --------------------------------------------------------------- fixup ----
// fp64 full re-score of flagged rows (grid-stride over compacted list);
// last-finishing block runs the fused finalize (loss + perplexity).
__global__ __launch_bounds__(256) void vq_fixup(const float* __restrict__ z,
                                                const float* __restrict__ emb,
                                                void* ws,
                                                float* __restrict__ out) {
  int tid = threadIdx.x;
  __shared__ __align__(16) float zrow[DIM];
  __shared__ double rd[256];
  __shared__ int    ri[256];
  __shared__ unsigned tick2;
  __shared__ float w4[4];

  const int n = (int)*WS_NFLAG(ws);

  for (int i = blockIdx.x; i < n; i += 1024) {
    int row = (int)WS_LIST(ws)[i];
    if (tid < 16) *(float4*)&zrow[tid * 4] = ((const float4*)(z + (size_t)row * DIM))[tid];
    __syncthreads();

    double bd = 1e300; int bi = 0x7fffffff;
    for (int c = tid; c < KCODE; c += 256) {
      const float4* e4 = (const float4*)(emb + (size_t)c * DIM);
      double dot = 0.0, e2 = 0.0;
#pragma unroll
      for (int t = 0; t < 16; ++t) {
        float4 v = e4[t];
        float4 zz = *(const float4*)&zrow[t * 4];
        dot = fma((double)zz.x, (double)v.x, dot);
        dot = fma((double)zz.y, (double)v.y, dot);
        dot = fma((double)zz.z, (double)v.z, dot);
        dot = fma((double)zz.w, (double)v.w, dot);
        e2  = fma((double)v.x, (double)v.x, e2);
        e2  = fma((double)v.y, (double)v.y, e2);
        e2  = fma((double)v.z, (double)v.z, e2);
        e2  = fma((double)v.w, (double)v.w, e2);
      }
      double dist = e2 - 2.0 * dot;
      if (dist < bd || (dist == bd && c < bi)) { bd = dist; bi = c; }
    }
    rd[tid] = bd; ri[tid] = bi;
    __syncthreads();
    for (int st = 128; st; st >>= 1) {
      if (tid < st) {
        double od = rd[tid + st]; int oi = ri[tid + st];
        if (od < rd[tid] || (od == rd[tid] && oi < ri[tid])) { rd[tid] = od; ri[tid] = oi; }
      }
      __syncthreads();
    }
    int wi = ri[0];
    if (tid < 16) {
      float4 e  = ((const float4*)(emb + (size_t)wi * DIM))[tid];
      float4 zz = *(const float4*)&zrow[tid * 4];
      float4 qv;
      qv.x = zz.x + (e.x - zz.x); qv.y = zz.y + (e.y - zz.y);
      qv.z = zz.z + (e.z - zz.z); qv.w = zz.w + (e.w - zz.w);
      ((float4*)(out + (size_t)row * DIM))[tid] = qv;
      float dx = zz.x - e.x, dy = zz.y - e.y, dz = zz.z - e.z, dw = zz.w - e.w;
      float part = dx * dx + dy * dy + dz * dz + dw * dw;
      part += __shfl_down(part, 8, 64);
      part += __shfl_down(part, 4, 64);
      part += __shfl_down(part, 2, 64);
      part += __shfl_down(part, 1, 64);
      if (tid == 0) {
        atomicAdd(WS_SSE(ws), part);
        atomicAdd(&WS_COUNTS(ws)[wi], 1);
      }
    }
    __syncthreads();
  }

  // fused finalize: last block to arrive computes loss + perplexity
  __threadfence();
  if (tid == 0) tick2 = atomicAdd(WS_FTICK(ws), 1u);
  __syncthreads();
  if (tick2 == 1023) {
    __threadfence();
    float part = 0.f;
    for (int c = tid; c < KCODE; c += 256) {
      float p = (float)WS_COUNTS(ws)[c] * (1.0f / (float)NROWS);
      part += p * logf(p + 1e-10f);
    }
    for (int off = 32; off; off >>= 1) part += __shfl_down(part, off, 64);
    if ((tid & 63) == 0) w4[tid >> 6] = part;
    __syncthreads();
    if (tid == 0) {
      float ent = (w4[0] + w4[1]) + (w4[2] + w4[3]);
      float perp = expf(-ent);
      perp = fminf(perp, (float)KCODE);
      if (!isfinite(perp)) perp = 0.f;
      out[(size_t)NROWS * DIM]     = 0.25f * (*WS_SSE(ws)) / (float)((size_t)NROWS * DIM);
      out[(size_t)NROWS * DIM + 1] = perp;
    }
  }
}

extern "C" void kernel_launch(void* const* d_in, const int* in_sizes, int n_in,
                              void* d_out, int out_size, void* d_ws, size_t ws_size,
                              hipStream_t stream) {
  const float* z   = (const float*)d_in[0];
  const float* emb = (const float*)d_in[1];
  float* out = (float*)d_out;
  (void)in_sizes; (void)n_in; (void)out_size; (void)ws_size;

  vq_init <<<64,   256, 0, stream>>>(emb, d_ws);
  vq_main <<<2048, 256, 0, stream>>>(z, emb, d_ws, out);
  vq_fixup<<<1024, 256, 0, stream>>>(z, emb, d_ws, out);
}

// Round 14
// 89.031 us; speedup vs baseline: 5.8962x; 5.8962x over previous
//
#include <hip/hip_runtime.h>
#include <math.h>

#define NROWS 65536      // B*T
#define DIM   64
#define KCODE 1024
#define TAU_M 2.5e-3f    // margin threshold: eps ~1.1e-3 (split+accum+5bit-trunc), ~2.3x headroom

typedef __attribute__((ext_vector_type(8))) short short8;
typedef __bf16 bf16_t;
typedef bf16_t bf16x8 __attribute__((ext_vector_type(8)));
typedef __attribute__((ext_vector_type(4))) float f32x4;

union B8 { bf16x8 v; short8 s; ushort u[8]; };

// ws layout (bytes):
//   [0      .. 262143]  ushort emb_frag  (64 tiles x 4KB: ks0hi,ks0lo,ks1hi,ks1lo x lane*16B)
//   [262144 .. 266239]  float  e2h[1024]  = -(||e||^2 - 64) / 2   (shifted: argmin-invariant)
//   [266240 .. 270335]  int    counts[1024]
//   [270336 .. 270339]  float  sse
//   [270340 .. 270343]  uint   nflag
//   [270400 .. 401471]  ushort list[NROWS]  (flagged row ids, compacted)
#define WS_EMBF(ws)   ((ushort*)(ws))
#define WS_E2H(ws)    ((float*)((char*)(ws) + 262144))
#define WS_COUNTS(ws) ((int*)((char*)(ws) + 266240))
#define WS_SSE(ws)    ((float*)((char*)(ws) + 270336))
#define WS_NFLAG(ws)  ((unsigned int*)((char*)(ws) + 270340))
#define WS_LIST(ws)   ((ushort*)((char*)(ws) + 270400))

__device__ __forceinline__ ushort f2bf(float x) {
  unsigned u = __float_as_uint(x);
  u += 0x7FFFu + ((u >> 16) & 1u);           // RNE
  return (ushort)(u >> 16);
}
__device__ __forceinline__ float bf2f(ushort h) {
  return __uint_as_float(((unsigned)h) << 16);
}

// ---------------------------------------------------------------- init ----
// grid 64 blocks x 256 threads; block = one 16-code tile (4KB fragment image).
__global__ __launch_bounds__(256) void vq_init(const float* __restrict__ emb, void* ws) {
  __shared__ __align__(16) ushort timg[2048];   // 4KB tile image
  __shared__ float e2p[256];

  const int g = blockIdx.x, t = threadIdx.x;    // g = global tile (16 codes)
  const int cl = t & 15;                        // local code (= MFMA col)
  const int d0 = (t >> 4) * 4;                  // dim range start
  const int gc = g * 16 + cl;

  const float4 v = *(const float4*)(emb + (size_t)gc * DIM + d0);
  float xs[4] = {v.x, v.y, v.z, v.w};
  float acc = 0.f;
#pragma unroll
  for (int u = 0; u < 4; ++u) {
    int d = d0 + u;
    float x = xs[u];
    ushort hs = f2bf(x);
    ushort ls = f2bf(x - bf2f(hs));
    int ks = d >> 5, kq = (d >> 3) & 3, e = d & 7;
    int lane = cl + kq * 16;
    int off = ks * 1024 + lane * 8 + e;         // ushort units within tile image
    timg[off] = hs;
    timg[off + 512] = ls;
    acc += x * x;
  }
  e2p[t] = acc;
  __syncthreads();
  if (t < 16) {
    float s = 0.f;
#pragma unroll
    for (int j = 0; j < 16; ++j) s += e2p[t + 16 * j];
    WS_E2H(ws)[g * 16 + t] = -0.5f * (s - 64.0f);   // shifted offset
    WS_COUNTS(ws)[g * 16 + t] = 0;
  }
  if (g == 0 && t == 0) { *WS_SSE(ws) = 0.f; *WS_NFLAG(ws) = 0u; }
  __syncthreads();
  ((int4*)WS_EMBF(ws))[g * 256 + t] = ((const int4*)timg)[t];
}

// ---------------------------------------------------------------- main ----
// grid 2048; block = 32 rows x ALL 1024 codes (in-block merge, no extra
// kernel, no fences — R13's __threadfence ticket pattern cost 6x).
// 4 waves = 2 row-halves x 2 code-halves; wave = 16 rows x 512 codes (32
// tiles). UNROLL 2 (was 4): 4-tile in-flight footprint was ~130-160 unified
// regs/wave -> ~3 waves/EU (the measured 35% occupancy ceiling across
// R10-R12 despite VGPR_Count=60, which counts arch regs only). 2 tiles in
// flight ~105 regs -> ~5 waves/EU: hide latency with TLP instead of ILP.
__global__ __launch_bounds__(256, 1) void vq_main(const float* __restrict__ z,
                                                  const float* __restrict__ emb,
                                                  void* ws,
                                                  float* __restrict__ outp) {
  __shared__ float  e2s[KCODE];  // 4KB
  __shared__ float2 redm[64];    // [wc][32 rows] top-2 m
  __shared__ int    redi[64];    // [wc][32 rows] argmax code
  __shared__ float  z2l[32];
  __shared__ int    win[32];

  const int tid  = threadIdx.x;
  const int lane = tid & 63, w = tid >> 6;
  const int wr = w >> 1, wc = w & 1;
  const int col  = lane & 15, kq = lane >> 4;
  const int rowbase = blockIdx.x * 32 + wr * 16;

  // stage e2h -> LDS (4KB)
  ((float4*)e2s)[tid] = ((const float4*)WS_E2H(ws))[tid];

  // A fragments: 1 row-group-of-16 x 2 ksteps, hi+lo, in registers all kernel.
  B8 ah[2], al[2];
  float z2p = 0.f;
  {
    int row = rowbase + col;
    const float* zr = z + (size_t)row * DIM;
#pragma unroll
    for (int ks = 0; ks < 2; ++ks) {
      const float4* p = (const float4*)(zr + ks * 32 + kq * 8);
      float4 x0 = p[0], x1 = p[1];
      float vv[8] = {x0.x, x0.y, x0.z, x0.w, x1.x, x1.y, x1.z, x1.w};
#pragma unroll
      for (int e = 0; e < 8; ++e) {
        ushort hs = f2bf(vv[e]);
        ah[ks].u[e] = hs;
        al[ks].u[e] = f2bf(vv[e] - bf2f(hs));
        z2p = fmaf(vv[e], vv[e], z2p);
      }
    }
    z2p += __shfl_xor(z2p, 16, 64);
    z2p += __shfl_xor(z2p, 32, 64);
  }

  float b1[4], b2[4];   // packed top-2 of m = z.e - (e^2-64)/2; low 5 bits = 31-t
#pragma unroll
  for (int q = 0; q < 4; ++q) { b1[q] = -3.4e38f; b2[q] = -3.4e38f; }

  __syncthreads();      // e2s ready

  // single incremented base + imm offsets for the 4 frag loads per tile
  const char* bb = (const char*)WS_EMBF(ws) + (size_t)(wc * 32) * 4096 + lane * 16;
  const int cidx0 = wc * 512 + col;

#pragma unroll 2
  for (int t = 0; t < 32; ++t) {
    B8 bh0, bl0, bh1, bl1;
    bh0.s = *(const short8*)(bb);
    bl0.s = *(const short8*)(bb + 1024);
    bh1.s = *(const short8*)(bb + 2048);
    bl1.s = *(const short8*)(bb + 3072);
    bb += 4096;

    float cinit = e2s[cidx0 + t * 16];
    f32x4 cc = {cinit, cinit, cinit, cinit};
    f32x4 zz4 = {0.f, 0.f, 0.f, 0.f};
    unsigned invT = 31u - (unsigned)t;

    // 2 independent chains, depth 3 each
    f32x4 p = __builtin_amdgcn_mfma_f32_16x16x32_bf16(ah[0].v, bh0.v, cc, 0, 0, 0);
    f32x4 q = __builtin_amdgcn_mfma_f32_16x16x32_bf16(ah[0].v, bl0.v, zz4, 0, 0, 0);
    p = __builtin_amdgcn_mfma_f32_16x16x32_bf16(al[0].v, bh0.v, p, 0, 0, 0);
    q = __builtin_amdgcn_mfma_f32_16x16x32_bf16(al[1].v, bh1.v, q, 0, 0, 0);
    p = __builtin_amdgcn_mfma_f32_16x16x32_bf16(ah[1].v, bh1.v, p, 0, 0, 0);
    q = __builtin_amdgcn_mfma_f32_16x16x32_bf16(ah[1].v, bl1.v, q, 0, 0, 0);

#pragma unroll
    for (int r = 0; r < 4; ++r) {
      float m = p[r] + q[r];
      unsigned mb = (__float_as_uint(m) & 0xFFFFFFE0u) | invT;
      float mp = __uint_as_float(mb);
      float nb2 = __builtin_amdgcn_fmed3f(mp, b1[r], b2[r]);
      b1[r] = fmaxf(b1[r], mp);
      b2[r] = nb2;
    }
  }

  // unpack to explicit (m, code) and top-2 merge across the 16 col-lanes
#pragma unroll
  for (int q = 0; q < 4; ++q) {
    unsigned u1 = __float_as_uint(b1[q]);
    int T1 = 31 - (int)(u1 & 0x1Fu);
    float m1 = __uint_as_float(u1 & 0xFFFFFFE0u);
    int   c1 = (wc * 32 + T1) * 16 + col;
    float m2 = __uint_as_float(__float_as_uint(b2[q]) & 0xFFFFFFE0u);
#pragma unroll
    for (int off = 1; off <= 8; off <<= 1) {
      float om1 = __shfl_xor(m1, off, 64);
      float om2 = __shfl_xor(m2, off, 64);
      int   oc1 = __shfl_xor(c1, off, 64);
      bool take = (om1 > m1) || (om1 == m1 && oc1 < c1);
      m2 = __builtin_amdgcn_fmed3f(m1, om1, fmaxf(m2, om2));
      m1 = take ? om1 : m1;
      c1 = take ? oc1 : c1;
    }
    if (col == 0) {
      int row = wr * 16 + kq * 4 + q;          // block-local 0..31
      redm[wc * 32 + row] = make_float2(m1, m2);
      redi[wc * 32 + row] = c1;
    }
  }
  if (wc == 0 && kq == 0) z2l[wr * 16 + col] = z2p;
  __syncthreads();

  // merge the 2 code-halves; flag / counts / SSE
  if (tid < 32) {
    int row = tid;
    float2 a = redm[row];       int ca = redi[row];
    float2 b = redm[32 + row];  int cb = redi[32 + row];
    bool take = (b.x > a.x);    // half0 codes < half1 codes: tie keeps half0
    float M1 = take ? b.x : a.x;
    int   C1 = take ? cb : ca;
    float M2 = __builtin_amdgcn_fmed3f(a.x, b.x, fmaxf(a.y, b.y));
    int grow = blockIdx.x * 32 + row;
    bool flg = (M1 - M2) < TAU_M;          // uncertified -> fp64 fixup
    win[row] = flg ? -1 : C1;
    if (!flg) {
      atomicAdd(&WS_COUNTS(ws)[C1], 1);
    } else {
      unsigned p = atomicAdd(WS_NFLAG(ws), 1u);
      WS_LIST(ws)[p] = (ushort)grow;
    }
    // ||z-e||^2 = ||z||^2 + 64 - 2*m1
    float ssep = flg ? 0.f : (z2l[row] + 64.0f - 2.0f * M1);
    ssep += __shfl_down(ssep, 16, 64);
    ssep += __shfl_down(ssep, 8, 64);
    ssep += __shfl_down(ssep, 4, 64);
    ssep += __shfl_down(ssep, 2, 64);
    ssep += __shfl_down(ssep, 1, 64);
    if (tid == 0) atomicAdd(WS_SSE(ws), ssep);
  }
  __syncthreads();

  // quantized_st == emb[winner] in value: write gather directly, no z re-read
  {
    int row = tid >> 3, qtr = tid & 7;
    int wv = win[row];
    if (wv >= 0) {
      size_t grow = (size_t)blockIdx.x * 32 + row;
      const float4* ep = (const float4*)(emb + (size_t)wv * DIM) + qtr * 2;
      float4* op = (float4*)(outp + grow * DIM) + qtr * 2;
      op[0] = ep[0]; op[1] = ep[1];
    }
  }
}

// --------------------------------------------------------------- fixup ----
// fp64 full re-score of flagged rows from the compacted list (load-balanced
// grid-stride); writes their out rows, counts, sse.
__global__ __launch_bounds__(256) void vq_fixup(const float* __restrict__ z,
                                                const float* __restrict__ emb,
                                                void* ws,
                                                float* __restrict__ out) {
  int tid = threadIdx.x;
  __shared__ __align__(16) float zrow[DIM];
  __shared__ double rd[256];
  __shared__ int    ri[256];

  const int n = (int)*WS_NFLAG(ws);

  for (int i = blockIdx.x; i < n; i += 1024) {
    int row = (int)WS_LIST(ws)[i];
    if (tid < 16) *(float4*)&zrow[tid * 4] = ((const float4*)(z + (size_t)row * DIM))[tid];
    __syncthreads();

    double bd = 1e300; int bi = 0x7fffffff;
    for (int c = tid; c < KCODE; c += 256) {
      const float4* e4 = (const float4*)(emb + (size_t)c * DIM);
      double dot = 0.0, e2 = 0.0;
#pragma unroll
      for (int t = 0; t < 16; ++t) {
        float4 v = e4[t];
        float4 zz = *(const float4*)&zrow[t * 4];
        dot = fma((double)zz.x, (double)v.x, dot);
        dot = fma((double)zz.y, (double)v.y, dot);
        dot = fma((double)zz.z, (double)v.z, dot);
        dot = fma((double)zz.w, (double)v.w, dot);
        e2  = fma((double)v.x, (double)v.x, e2);
        e2  = fma((double)v.y, (double)v.y, e2);
        e2  = fma((double)v.z, (double)v.z, e2);
        e2  = fma((double)v.w, (double)v.w, e2);
      }
      double dist = e2 - 2.0 * dot;
      if (dist < bd || (dist == bd && c < bi)) { bd = dist; bi = c; }
    }
    rd[tid] = bd; ri[tid] = bi;
    __syncthreads();
    for (int st = 128; st; st >>= 1) {
      if (tid < st) {
        double od = rd[tid + st]; int oi = ri[tid + st];
        if (od < rd[tid] || (od == rd[tid] && oi < ri[tid])) { rd[tid] = od; ri[tid] = oi; }
      }
      __syncthreads();
    }
    int wi = ri[0];
    if (tid < 16) {
      float4 e  = ((const float4*)(emb + (size_t)wi * DIM))[tid];
      float4 zz = *(const float4*)&zrow[tid * 4];
      float4 qv;
      qv.x = zz.x + (e.x - zz.x); qv.y = zz.y + (e.y - zz.y);
      qv.z = zz.z + (e.z - zz.z); qv.w = zz.w + (e.w - zz.w);
      ((float4*)(out + (size_t)row * DIM))[tid] = qv;
      float dx = zz.x - e.x, dy = zz.y - e.y, dz = zz.z - e.z, dw = zz.w - e.w;
      float part = dx * dx + dy * dy + dz * dz + dw * dw;
      part += __shfl_down(part, 8, 64);
      part += __shfl_down(part, 4, 64);
      part += __shfl_down(part, 2, 64);
      part += __shfl_down(part, 1, 64);
      if (tid == 0) {
        atomicAdd(WS_SSE(ws), part);
        atomicAdd(&WS_COUNTS(ws)[wi], 1);
      }
    }
    __syncthreads();
  }
}

// ------------------------------------------------------------ finalize ----
__global__ __launch_bounds__(256) void vq_finalize(void* ws, float* __restrict__ out) {
  int tid = threadIdx.x;
  __shared__ float w4[4];
  float part = 0.f;
  for (int c = tid; c < KCODE; c += 256) {
    float p = (float)WS_COUNTS(ws)[c] * (1.0f / (float)NROWS);
    part += p * logf(p + 1e-10f);
  }
  for (int off = 32; off; off >>= 1) part += __shfl_down(part, off, 64);
  if ((tid & 63) == 0) w4[tid >> 6] = part;
  __syncthreads();
  if (tid == 0) {
    float ent = (w4[0] + w4[1]) + (w4[2] + w4[3]);
    float perp = expf(-ent);
    perp = fminf(perp, (float)KCODE);
    if (!isfinite(perp)) perp = 0.f;
    out[(size_t)NROWS * DIM]     = 0.25f * (*WS_SSE(ws)) / (float)((size_t)NROWS * DIM);
    out[(size_t)NROWS * DIM + 1] = perp;
  }
}

extern "C" void kernel_launch(void* const* d_in, const int* in_sizes, int n_in,
                              void* d_out, int out_size, void* d_ws, size_t ws_size,
                              hipStream_t stream) {
  const float* z   = (const float*)d_in[0];
  const float* emb = (const float*)d_in[1];
  float* out = (float*)d_out;
  (void)in_sizes; (void)n_in; (void)out_size; (void)ws_size;

  vq_init    <<<64,   256, 0, stream>>>(emb, d_ws);
  vq_main    <<<2048, 256, 0, stream>>>(z, emb, d_ws, out);
  vq_fixup   <<<1024, 256, 0, stream>>>(z, emb, d_ws, out);
  vq_finalize<<<1,    256, 0, stream>>>(d_ws, out);
}

// Round 15
// 77.784 us; speedup vs baseline: 6.7487x; 1.1446x over previous
//
#include <hip/hip_runtime.h>
#include <math.h>

#define NROWS 65536      // B*T
#define DIM   64
#define KCODE 1024
#define TAU_M 2.5e-3f    // margin threshold: eps ~6e-4 (split+accum+4bit-trunc), >4x headroom

typedef __attribute__((ext_vector_type(8))) short short8;
typedef __bf16 bf16_t;
typedef bf16_t bf16x8 __attribute__((ext_vector_type(8)));
typedef __attribute__((ext_vector_type(4))) float f32x4;

union B8 { bf16x8 v; short8 s; ushort u[8]; };

// ws layout (bytes):
//   [0      .. 262143]  ushort emb_frag  (64 tiles x 4KB: ks0hi,ks0lo,ks1hi,ks1lo x lane*16B)
//   [262144 .. 266239]  float  e2h[1024]  = -(||e||^2 - 64) / 2   (shifted: argmin-invariant)
//   [266240 .. 270335]  int    counts[1024]
//   [270336 .. 270339]  float  sse
//   [270340 .. 270343]  uint   nflag
//   [270400 .. 401471]  ushort list[NROWS]  (flagged row ids, compacted)
#define WS_EMBF(ws)   ((ushort*)(ws))
#define WS_E2H(ws)    ((float*)((char*)(ws) + 262144))
#define WS_COUNTS(ws) ((int*)((char*)(ws) + 266240))
#define WS_SSE(ws)    ((float*)((char*)(ws) + 270336))
#define WS_NFLAG(ws)  ((unsigned int*)((char*)(ws) + 270340))
#define WS_LIST(ws)   ((ushort*)((char*)(ws) + 270400))

__device__ __forceinline__ ushort f2bf(float x) {
  unsigned u = __float_as_uint(x);
  u += 0x7FFFu + ((u >> 16) & 1u);           // RNE
  return (ushort)(u >> 16);
}
__device__ __forceinline__ float bf2f(ushort h) {
  return __uint_as_float(((unsigned)h) << 16);
}

// ---------------------------------------------------------------- init ----
// grid 64 blocks x 256 threads; block = one 16-code tile (4KB fragment image).
__global__ __launch_bounds__(256) void vq_init(const float* __restrict__ emb, void* ws) {
  __shared__ __align__(16) ushort timg[2048];   // 4KB tile image
  __shared__ float e2p[256];

  const int g = blockIdx.x, t = threadIdx.x;    // g = global tile (16 codes)
  const int cl = t & 15;                        // local code (= MFMA col)
  const int d0 = (t >> 4) * 4;                  // dim range start
  const int gc = g * 16 + cl;

  const float4 v = *(const float4*)(emb + (size_t)gc * DIM + d0);
  float xs[4] = {v.x, v.y, v.z, v.w};
  float acc = 0.f;
#pragma unroll
  for (int u = 0; u < 4; ++u) {
    int d = d0 + u;
    float x = xs[u];
    ushort hs = f2bf(x);
    ushort ls = f2bf(x - bf2f(hs));
    int ks = d >> 5, kq = (d >> 3) & 3, e = d & 7;
    int lane = cl + kq * 16;
    int off = ks * 1024 + lane * 8 + e;         // ushort units within tile image
    timg[off] = hs;
    timg[off + 512] = ls;
    acc += x * x;
  }
  e2p[t] = acc;
  __syncthreads();
  if (t < 16) {
    float s = 0.f;
#pragma unroll
    for (int j = 0; j < 16; ++j) s += e2p[t + 16 * j];
    WS_E2H(ws)[g * 16 + t] = -0.5f * (s - 64.0f);   // shifted offset
    WS_COUNTS(ws)[g * 16 + t] = 0;
  }
  if (g == 0 && t == 0) { *WS_SSE(ws) = 0.f; *WS_NFLAG(ws) = 0u; }
  __syncthreads();
  ((int4*)WS_EMBF(ws))[g * 256 + t] = ((const int4*)timg)[t];
}

// ---------------------------------------------------------------- main ----
// grid 1024; block = 512 threads = 8 waves = 2 row-halves x 4 code-quarters;
// block covers 64 rows x ALL 1024 codes -> 4-quarter merge stays in LDS (no
// merge kernel, no fences). Each wave is exactly R11's proven-47us shape:
// 32 rows x 256 codes (16 tiles), unroll 4, ~56 arch VGPRs (fits even a
// 64-reg clamp on 512-thr blocks -> no spill expected; FETCH is the tell).
__global__ __launch_bounds__(512, 1) void vq_main(const float* __restrict__ z,
                                                  const float* __restrict__ emb,
                                                  void* ws,
                                                  float* __restrict__ outp) {
  __shared__ float  e2s[KCODE];  // 4KB
  __shared__ float2 redm[256];   // [wq][64 rows] top-2 m
  __shared__ int    redi[256];   // [wq][64 rows] argmax code
  __shared__ float  z2l[64];
  __shared__ int    win[64];

  const int tid  = threadIdx.x;
  const int lane = tid & 63, w = tid >> 6;
  const int wr = w >> 2, wq = w & 3;
  const int col  = lane & 15, kq = lane >> 4;
  const int rowbase = blockIdx.x * 64 + wr * 32;
  const int tbase = wq * 16;                     // first tile of this wave

  // stage e2h -> LDS (4KB)
  if (tid < 256) ((float4*)e2s)[tid] = ((const float4*)WS_E2H(ws))[tid];

  // A fragments: 2 row-groups-of-16 x 2 ksteps, hi+lo, in registers all kernel.
  B8 ah[2][2], al[2][2];
  float z2p[2];
#pragma unroll
  for (int g = 0; g < 2; ++g) {
    int row = rowbase + g * 16 + col;
    const float* zr = z + (size_t)row * DIM;
    float acc2 = 0.f;
#pragma unroll
    for (int ks = 0; ks < 2; ++ks) {
      const float4* p = (const float4*)(zr + ks * 32 + kq * 8);
      float4 x0 = p[0], x1 = p[1];
      float vv[8] = {x0.x, x0.y, x0.z, x0.w, x1.x, x1.y, x1.z, x1.w};
#pragma unroll
      for (int e = 0; e < 8; ++e) {
        ushort hs = f2bf(vv[e]);
        ah[g][ks].u[e] = hs;
        al[g][ks].u[e] = f2bf(vv[e] - bf2f(hs));
        acc2 = fmaf(vv[e], vv[e], acc2);
      }
    }
    z2p[g] = acc2;
  }
#pragma unroll
  for (int g = 0; g < 2; ++g) {
    z2p[g] += __shfl_xor(z2p[g], 16, 64);
    z2p[g] += __shfl_xor(z2p[g], 32, 64);
  }

  float b1[8], b2[8];   // packed top-2 of m = z.e - (e^2-64)/2; low 4 bits = 15-t
#pragma unroll
  for (int q = 0; q < 8; ++q) { b1[q] = -3.4e38f; b2[q] = -3.4e38f; }

  __syncthreads();      // e2s ready

  // single incremented base + imm offsets (1024/2048/3072) for the 4 frag loads
  const char* bb = (const char*)WS_EMBF(ws) + (size_t)tbase * 4096 + lane * 16;
  const int cidx0 = tbase * 16 + col;

#pragma unroll 4
  for (int t = 0; t < 16; ++t) {
    B8 bh0, bl0, bh1, bl1;
    bh0.s = *(const short8*)(bb);
    bl0.s = *(const short8*)(bb + 1024);
    bh1.s = *(const short8*)(bb + 2048);
    bl1.s = *(const short8*)(bb + 3072);
    bb += 4096;

    float cinit = e2s[cidx0 + t * 16];
    f32x4 cc = {cinit, cinit, cinit, cinit};
    f32x4 zz4 = {0.f, 0.f, 0.f, 0.f};
    unsigned invT = 15u - (unsigned)t;

    // 4 independent chains, depth 3 each
    f32x4 p0 = __builtin_amdgcn_mfma_f32_16x16x32_bf16(ah[0][0].v, bh0.v, cc, 0, 0, 0);
    f32x4 p1 = __builtin_amdgcn_mfma_f32_16x16x32_bf16(ah[1][0].v, bh0.v, cc, 0, 0, 0);
    f32x4 q0 = __builtin_amdgcn_mfma_f32_16x16x32_bf16(ah[0][0].v, bl0.v, zz4, 0, 0, 0);
    f32x4 q1 = __builtin_amdgcn_mfma_f32_16x16x32_bf16(ah[1][0].v, bl0.v, zz4, 0, 0, 0);
    p0 = __builtin_amdgcn_mfma_f32_16x16x32_bf16(al[0][0].v, bh0.v, p0, 0, 0, 0);
    p1 = __builtin_amdgcn_mfma_f32_16x16x32_bf16(al[1][0].v, bh0.v, p1, 0, 0, 0);
    q0 = __builtin_amdgcn_mfma_f32_16x16x32_bf16(al[0][1].v, bh1.v, q0, 0, 0, 0);
    q1 = __builtin_amdgcn_mfma_f32_16x16x32_bf16(al[1][1].v, bh1.v, q1, 0, 0, 0);
    p0 = __builtin_amdgcn_mfma_f32_16x16x32_bf16(ah[0][1].v, bh1.v, p0, 0, 0, 0);
    p1 = __builtin_amdgcn_mfma_f32_16x16x32_bf16(ah[1][1].v, bh1.v, p1, 0, 0, 0);
    q0 = __builtin_amdgcn_mfma_f32_16x16x32_bf16(ah[0][1].v, bl1.v, q0, 0, 0, 0);
    q1 = __builtin_amdgcn_mfma_f32_16x16x32_bf16(ah[1][1].v, bl1.v, q1, 0, 0, 0);

#pragma unroll
    for (int g = 0; g < 2; ++g) {
      f32x4 pv = g ? p1 : p0;
      f32x4 qv = g ? q1 : q0;
#pragma unroll
      for (int r = 0; r < 4; ++r) {
        int q = g * 4 + r;
        float m = pv[r] + qv[r];
        unsigned mb = (__float_as_uint(m) & 0xFFFFFFF0u) | invT;
        float mp = __uint_as_float(mb);
        float nb2 = __builtin_amdgcn_fmed3f(mp, b1[q], b2[q]);
        b1[q] = fmaxf(b1[q], mp);
        b2[q] = nb2;
      }
    }
  }

  // unpack to explicit (m, code) and top-2 merge across the 16 col-lanes
#pragma unroll
  for (int q = 0; q < 8; ++q) {
    unsigned u1 = __float_as_uint(b1[q]);
    int T1 = 15 - (int)(u1 & 0xFu);
    float m1 = __uint_as_float(u1 & 0xFFFFFFF0u);
    int   c1 = (tbase + T1) * 16 + col;
    float m2 = __uint_as_float(__float_as_uint(b2[q]) & 0xFFFFFFF0u);
#pragma unroll
    for (int off = 1; off <= 8; off <<= 1) {
      float om1 = __shfl_xor(m1, off, 64);
      float om2 = __shfl_xor(m2, off, 64);
      int   oc1 = __shfl_xor(c1, off, 64);
      bool take = (om1 > m1) || (om1 == m1 && oc1 < c1);
      m2 = __builtin_amdgcn_fmed3f(m1, om1, fmaxf(m2, om2));
      m1 = take ? om1 : m1;
      c1 = take ? oc1 : c1;
    }
    if (col == 0) {
      int row = wr * 32 + (q >> 2) * 16 + kq * 4 + (q & 3);   // block-local 0..63
      redm[wq * 64 + row] = make_float2(m1, m2);
      redi[wq * 64 + row] = c1;
    }
  }
  if (wq == 0 && kq == 0) {
#pragma unroll
    for (int g = 0; g < 2; ++g) z2l[wr * 32 + g * 16 + col] = z2p[g];
  }
  __syncthreads();

  // merge the 4 code-quarters; flag / counts / SSE
  if (tid < 64) {
    int row = tid;
    float M1 = -3.4e38f, M2 = -3.4e38f; int C1 = 0x7fffffff;
#pragma unroll
    for (int e = 0; e < 4; ++e) {       // quarters ascend in code: > keeps lowest
      float2 v = redm[e * 64 + row];
      int    ci = redi[e * 64 + row];
      bool take = (v.x > M1) || (v.x == M1 && ci < C1);
      M2 = __builtin_amdgcn_fmed3f(M1, v.x, fmaxf(M2, v.y));
      M1 = take ? v.x : M1;
      C1 = take ? ci : C1;
    }
    int grow = blockIdx.x * 64 + row;
    bool flg = (M1 - M2) < TAU_M;       // uncertified -> fp64 fixup
    win[row] = flg ? -1 : C1;
    if (!flg) {
      atomicAdd(&WS_COUNTS(ws)[C1], 1);
    } else {
      unsigned p = atomicAdd(WS_NFLAG(ws), 1u);
      WS_LIST(ws)[p] = (ushort)grow;
    }
    // ||z-e||^2 = ||z||^2 + 64 - 2*m1
    float ssep = flg ? 0.f : (z2l[row] + 64.0f - 2.0f * M1);
#pragma unroll
    for (int off = 32; off; off >>= 1) ssep += __shfl_down(ssep, off, 64);
    if (tid == 0) atomicAdd(WS_SSE(ws), ssep);
  }
  __syncthreads();

  // quantized_st == emb[winner] in value: write gather directly, no z re-read
  {
    int row = tid >> 3, qtr = tid & 7;
    int wv = win[row];
    if (wv >= 0) {
      size_t grow = (size_t)blockIdx.x * 64 + row;
      const float4* ep = (const float4*)(emb + (size_t)wv * DIM) + qtr * 2;
      float4* op = (float4*)(outp + grow * DIM) + qtr * 2;
      op[0] = ep[0]; op[1] = ep[1];
    }
  }
}

// --------------------------------------------------------------- fixup ----
// fp64 full re-score of flagged rows from the compacted list (load-balanced
// grid-stride); writes their out rows, counts, sse.
__global__ __launch_bounds__(256) void vq_fixup(const float* __restrict__ z,
                                                const float* __restrict__ emb,
                                                void* ws,
                                                float* __restrict__ out) {
  int tid = threadIdx.x;
  __shared__ __align__(16) float zrow[DIM];
  __shared__ double rd[256];
  __shared__ int    ri[256];

  const int n = (int)*WS_NFLAG(ws);

  for (int i = blockIdx.x; i < n; i += 1024) {
    int row = (int)WS_LIST(ws)[i];
    if (tid < 16) *(float4*)&zrow[tid * 4] = ((const float4*)(z + (size_t)row * DIM))[tid];
    __syncthreads();

    double bd = 1e300; int bi = 0x7fffffff;
    for (int c = tid; c < KCODE; c += 256) {
      const float4* e4 = (const float4*)(emb + (size_t)c * DIM);
      double dot = 0.0, e2 = 0.0;
#pragma unroll
      for (int t = 0; t < 16; ++t) {
        float4 v = e4[t];
        float4 zz = *(const float4*)&zrow[t * 4];
        dot = fma((double)zz.x, (double)v.x, dot);
        dot = fma((double)zz.y, (double)v.y, dot);
        dot = fma((double)zz.z, (double)v.z, dot);
        dot = fma((double)zz.w, (double)v.w, dot);
        e2  = fma((double)v.x, (double)v.x, e2);
        e2  = fma((double)v.y, (double)v.y, e2);
        e2  = fma((double)v.z, (double)v.z, e2);
        e2  = fma((double)v.w, (double)v.w, e2);
      }
      double dist = e2 - 2.0 * dot;
      if (dist < bd || (dist == bd && c < bi)) { bd = dist; bi = c; }
    }
    rd[tid] = bd; ri[tid] = bi;
    __syncthreads();
    for (int st = 128; st; st >>= 1) {
      if (tid < st) {
        double od = rd[tid + st]; int oi = ri[tid + st];
        if (od < rd[tid] || (od == rd[tid] && oi < ri[tid])) { rd[tid] = od; ri[tid] = oi; }
      }
      __syncthreads();
    }
    int wi = ri[0];
    if (tid < 16) {
      float4 e  = ((const float4*)(emb + (size_t)wi * DIM))[tid];
      float4 zz = *(const float4*)&zrow[tid * 4];
      float4 qv;
      qv.x = zz.x + (e.x - zz.x); qv.y = zz.y + (e.y - zz.y);
      qv.z = zz.z + (e.z - zz.z); qv.w = zz.w + (e.w - zz.w);
      ((float4*)(out + (size_t)row * DIM))[tid] = qv;
      float dx = zz.x - e.x, dy = zz.y - e.y, dz = zz.z - e.z, dw = zz.w - e.w;
      float part = dx * dx + dy * dy + dz * dz + dw * dw;
      part += __shfl_down(part, 8, 64);
      part += __shfl_down(part, 4, 64);
      part += __shfl_down(part, 2, 64);
      part += __shfl_down(part, 1, 64);
      if (tid == 0) {
        atomicAdd(WS_SSE(ws), part);
        atomicAdd(&WS_COUNTS(ws)[wi], 1);
      }
    }
    __syncthreads();
  }
}

// ------------------------------------------------------------ finalize ----
__global__ __launch_bounds__(256) void vq_finalize(void* ws, float* __restrict__ out) {
  int tid = threadIdx.x;
  __shared__ float w4[4];
  float part = 0.f;
  for (int c = tid; c < KCODE; c += 256) {
    float p = (float)WS_COUNTS(ws)[c] * (1.0f / (float)NROWS);
    part += p * logf(p + 1e-10f);
  }
  for (int off = 32; off; off >>= 1) part += __shfl_down(part, off, 64);
  if ((tid & 63) == 0) w4[tid >> 6] = part;
  __syncthreads();
  if (tid == 0) {
    float ent = (w4[0] + w4[1]) + (w4[2] + w4[3]);
    float perp = expf(-ent);
    perp = fminf(perp, (float)KCODE);
    if (!isfinite(perp)) perp = 0.f;
    out[(size_t)NROWS * DIM]     = 0.25f * (*WS_SSE(ws)) / (float)((size_t)NROWS * DIM);
    out[(size_t)NROWS * DIM + 1] = perp;
  }
}

extern "C" void kernel_launch(void* const* d_in, const int* in_sizes, int n_in,
                              void* d_out, int out_size, void* d_ws, size_t ws_size,
                              hipStream_t stream) {
  const float* z   = (const float*)d_in[0];
  const float* emb = (const float*)d_in[1];
  float* out = (float*)d_out;
  (void)in_sizes; (void)n_in; (void)out_size; (void)ws_size;

  vq_init    <<<64,   256, 0, stream>>>(emb, d_ws);
  vq_main    <<<NROWS / 64, 512, 0, stream>>>(z, emb, d_ws, out);
  vq_fixup   <<<1024, 256, 0, stream>>>(z, emb, d_ws, out);
  vq_finalize<<<1,    256, 0, stream>>>(d_ws, out);
}